// Round 2
// baseline (709.179 us; speedup 1.0000x reference)
//
#include <hip/hip_runtime.h>

// HyperbolicGraphPooling: out[g,:] = sum_{i: batch[i]==g} f[i,:] * sigmoid(f[i,:]@W + b)
// N=500000, C=256, G=2048, batch sorted ascending.
//
// R7: MEASUREMENT ROUND. R6 proved the 2 GB workspace poison fill (~322 us) is
// unconditional and inside the timed region. Remaining ambiguity: is the main
// kernel ~300 us (627-322) or ~90 us (with ~215 us of further hidden harness
// work below the top-5 duration cut)? Static models (VALU issue, outstanding-
// load latency coverage, LDS chain) all say the kernel should be <=100 us, but
// counters can't confirm: the kernel row is hidden below the 318+ us fills.
//
// Instrument: launch the IDENTICAL verified kernel TWICE. Idempotent (every
// out element written unconditionally from read-only inputs; serial WAW in
// one stream is deterministic), and the second pass gets ~0% L3 reuse
// (512 MB cyclic stream > 256 MB L3). Therefore:
//     kernel_time = dur_us(R7) - 627.0
// H2 (kernel ~90us, harness floor ~537): expect dur ~705-740 -> ROOFLINE next.
// H1 (kernel ~300us): expect dur ~880-950 -> ~220us headroom, attack memory path.
//
// Kernel body is byte-for-byte the verified R6 kernel.

constexpr int kChannels  = 256;
constexpr int kVecPerRow = kChannels / 4;  // 64 float4 per row

typedef float vfloat4 __attribute__((ext_vector_type(4)));

__device__ inline float sigmoidf(float x) { return 1.0f / (1.0f + __expf(-x)); }

__device__ inline float dot4(vfloat4 a, vfloat4 b) {
    return a[0] * b[0] + a[1] * b[1] + a[2] * b[2] + a[3] * b[3];
}

__global__ __launch_bounds__(256, 2)
void hgp_seg_kernel(const float* __restrict__ features,
                    const int*   __restrict__ batch,
                    const float* __restrict__ W_att,
                    const float* __restrict__ b_att,
                    float*       __restrict__ out,
                    int n_nodes) {
    const int g    = blockIdx.x;          // segment id
    const int wv   = threadIdx.x >> 6;    // wave 0..3
    const int lane = threadIdx.x & 63;
    const int sub  = lane & 15;           // position within 16-lane group
    const int grp  = lane >> 4;           // which of the 4 rows this lane handles

    // Dual bitwise binary search: s0 = #elements < g  (= seg_start),
    // s1 = #elements < g+1 (= seg_end). Two independent dependence chains
    // (ILP=2), 20 steps each (2^20 > 500000). Exec-uniform: no divergence;
    // loads broadcast from the same cacheline across all lanes.
    int s0 = 0, s1 = 0;
    const int g1 = g + 1;
    #pragma unroll
    for (int step = 1 << 19; step > 0; step >>= 1) {
        const int c0 = s0 + step;
        const int c1 = s1 + step;
        if (c0 <= n_nodes && batch[c0 - 1] < g)  s0 = c0;
        if (c1 <= n_nodes && batch[c1 - 1] < g1) s1 = c1;
    }
    const int seg_start = s0;
    const int seg_end   = s1;
    const int seg_len   = seg_end - seg_start;

    // Wave's contiguous quarter of the segment.
    const int q   = (seg_len + 3) >> 2;
    const int ws_ = seg_start + wv * q;
    const int we_ = min(ws_ + q, seg_end);

    const vfloat4* __restrict__ frow = reinterpret_cast<const vfloat4*>(features);
    const vfloat4* __restrict__ W4   = reinterpret_cast<const vfloat4*>(W_att);

    // Lane's W fragment: channels {4*(sub+16j) .. +3}, j=0..3.
    const vfloat4 w0 = W4[sub];
    const vfloat4 w1 = W4[sub + 16];
    const vfloat4 w2 = W4[sub + 32];
    const vfloat4 w3 = W4[sub + 48];
    const float bias = b_att[0];

    vfloat4 acc0 = 0.f, acc1 = 0.f, acc2 = 0.f, acc3 = 0.f;

    int n = ws_;
    // 3-stage pipeline buffers (stage = 4 rows; this wave's lane reads 4x16B).
    vfloat4 a0, a1, a2, a3;   // rows n .. n+3
    vfloat4 b0, b1, b2, b3;   // rows n+4 .. n+7

    if (n + 4 <= we_) {
        const size_t rb = (size_t)(n + grp) * kVecPerRow + sub;
        a0 = __builtin_nontemporal_load(&frow[rb]);
        a1 = __builtin_nontemporal_load(&frow[rb + 16]);
        a2 = __builtin_nontemporal_load(&frow[rb + 32]);
        a3 = __builtin_nontemporal_load(&frow[rb + 48]);
    }
    if (n + 8 <= we_) {
        const size_t rb = (size_t)(n + 4 + grp) * kVecPerRow + sub;
        b0 = __builtin_nontemporal_load(&frow[rb]);
        b1 = __builtin_nontemporal_load(&frow[rb + 16]);
        b2 = __builtin_nontemporal_load(&frow[rb + 32]);
        b3 = __builtin_nontemporal_load(&frow[rb + 48]);
    }

    #define HGP_COMPUTE(r0, r1, r2, r3)                                        \
        do {                                                                   \
            float p = dot4(r0, w0) + dot4(r1, w1) + dot4(r2, w2) + dot4(r3, w3); \
            p += __shfl_xor(p, 8, 64);                                         \
            p += __shfl_xor(p, 4, 64);                                         \
            p += __shfl_xor(p, 2, 64);                                         \
            p += __shfl_xor(p, 1, 64);                                         \
            const float gate = sigmoidf(p + bias);                             \
            acc0 += r0 * gate; acc1 += r1 * gate;                              \
            acc2 += r2 * gate; acc3 += r3 * gate;                              \
        } while (0)

    for (; n + 12 <= we_; n += 4) {
        // Issue stage-3 loads (rows n+8..n+11) before consuming stage-1.
        const size_t rb = (size_t)(n + 8 + grp) * kVecPerRow + sub;
        vfloat4 c0 = __builtin_nontemporal_load(&frow[rb]);
        vfloat4 c1 = __builtin_nontemporal_load(&frow[rb + 16]);
        vfloat4 c2 = __builtin_nontemporal_load(&frow[rb + 32]);
        vfloat4 c3 = __builtin_nontemporal_load(&frow[rb + 48]);

        HGP_COMPUTE(a0, a1, a2, a3);

        a0 = b0; a1 = b1; a2 = b2; a3 = b3;
        b0 = c0; b1 = c1; b2 = c2; b3 = c3;
    }

    if (n + 4 <= we_) {  // drain stage 1
        HGP_COMPUTE(a0, a1, a2, a3);
        n += 4;
        a0 = b0; a1 = b1; a2 = b2; a3 = b3;
    }
    if (n + 4 <= we_) {  // drain stage 2
        HGP_COMPUTE(a0, a1, a2, a3);
        n += 4;
    }

    if (n < we_) {  // masked tail: 1..3 rows; out-of-range groups contribute 0
        const int  row = n + grp;
        const bool ok  = row < we_;
        const size_t rb = (size_t)(ok ? row : we_ - 1) * kVecPerRow + sub;
        vfloat4 t0 = __builtin_nontemporal_load(&frow[rb]);
        vfloat4 t1 = __builtin_nontemporal_load(&frow[rb + 16]);
        vfloat4 t2 = __builtin_nontemporal_load(&frow[rb + 32]);
        vfloat4 t3 = __builtin_nontemporal_load(&frow[rb + 48]);
        if (!ok) { t0 = 0.f; t1 = 0.f; t2 = 0.f; t3 = 0.f; }
        HGP_COMPUTE(t0, t1, t2, t3);
    }
    #undef HGP_COMPUTE

    // 16 partial channel-vectors (4 waves x 4 groups) -> LDS -> one store.
    __shared__ float lds[16][kChannels];  // 16 KB
    {
        const int slot = wv * 4 + grp;
        vfloat4* dst = reinterpret_cast<vfloat4*>(lds[slot]);
        dst[sub]      = acc0;
        dst[sub + 16] = acc1;
        dst[sub + 32] = acc2;
        dst[sub + 48] = acc3;
    }
    __syncthreads();

    const int t = threadIdx.x;  // 0..255 == channel
    float s = 0.f;
    #pragma unroll
    for (int k = 0; k < 16; ++k) s += lds[k][t];
    out[(size_t)g * kChannels + t] = s;
}

extern "C" void kernel_launch(void* const* d_in, const int* in_sizes, int n_in,
                              void* d_out, int out_size, void* d_ws, size_t ws_size,
                              hipStream_t stream) {
    const float* features = (const float*)d_in[0];
    const int*   batch    = (const int*)d_in[1];
    const float* W_att    = (const float*)d_in[2];
    const float* b_att    = (const float*)d_in[3];
    float*       out      = (float*)d_out;
    (void)d_ws; (void)ws_size;  // unused — the 2 GB poison fill happens anyway (R6)

    const int n_nodes    = in_sizes[1];          // one batch entry per node
    const int num_graphs = out_size / kChannels; // 2048

    // R7 instrument: TWO identical launches. Kernel is idempotent (every out
    // element written unconditionally), so results are bit-identical; the
    // second launch costs exactly one kernel-time (no L3 reuse at 512 MB).
    //   kernel_time = dur_us(this round) - 627.0 us (R6 baseline)
    hgp_seg_kernel<<<num_graphs, 256, 0, stream>>>(features, batch, W_att, b_att,
                                                   out, n_nodes);
    hgp_seg_kernel<<<num_graphs, 256, 0, stream>>>(features, batch, W_att, b_att,
                                                   out, n_nodes);
}

// Round 3
// 626.161 us; speedup vs baseline: 1.1326x; 1.1326x over previous
//
#include <hip/hip_runtime.h>

// HyperbolicGraphPooling: out[g,:] = sum_{i: batch[i]==g} f[i,:] * sigmoid(f[i,:]@W + b)
// N=500000, C=256, G=2048, batch sorted ascending.
//
// R8: PRODUCTION (single launch). Session conclusions, with evidence:
//  - Kernel time = 82.2 us, measured by difference (R7 double-launch 709.18
//    minus R6 single-launch 627.01). Mandatory traffic 516 MB @ ~6.4 TB/s
//    achievable => 80.6 us floor. Kernel is at ~98% of the HBM roofline.
//  - The other ~545 us of dur_us is harness-fixed: an unconditional 2.048 GB
//    workspace re-poison (fillBufferAligned, ~320 us @ 6.4 TB/s, present even
//    when d_ws is never touched — R6 experiment) plus ~225 us of further
//    per-iteration restore work below the rocprof top-5 cut.
//  - No precision lever (reference is fp32 in/out); no reuse structure
//    (features read exactly once); compute ~8 us of SIMD time, fully hidden.
//
// Structure: one block per segment; 4 waves take contiguous quarters; within
// a wave, 4x16-lane groups each own one row (lane holds 16 channels as 4x
// float4). Dual bitwise binary search recovers [seg_start,seg_end) from the
// sorted batch array (uniform, L2-hot, ~7 us total). 3-stage software
// pipeline of nontemporal 16B loads (12 in flight/wave); 4-step shfl_xor
// butterfly reduces 4 row-dots at once; sigmoid gate; FMA into per-lane
// accumulators; LDS cross-wave combine; one coalesced 1 KB store per block.
// Empty segments write zeros unconditionally (poison-safe, no memset).

constexpr int kChannels  = 256;
constexpr int kVecPerRow = kChannels / 4;  // 64 float4 per row

typedef float vfloat4 __attribute__((ext_vector_type(4)));

__device__ inline float sigmoidf(float x) { return 1.0f / (1.0f + __expf(-x)); }

__device__ inline float dot4(vfloat4 a, vfloat4 b) {
    return a[0] * b[0] + a[1] * b[1] + a[2] * b[2] + a[3] * b[3];
}

__global__ __launch_bounds__(256, 2)
void hgp_seg_kernel(const float* __restrict__ features,
                    const int*   __restrict__ batch,
                    const float* __restrict__ W_att,
                    const float* __restrict__ b_att,
                    float*       __restrict__ out,
                    int n_nodes) {
    const int g    = blockIdx.x;          // segment id
    const int wv   = threadIdx.x >> 6;    // wave 0..3
    const int lane = threadIdx.x & 63;
    const int sub  = lane & 15;           // position within 16-lane group
    const int grp  = lane >> 4;           // which of the 4 rows this lane handles

    // Dual bitwise binary search: s0 = #elements < g  (= seg_start),
    // s1 = #elements < g+1 (= seg_end). Two independent dependence chains
    // (ILP=2), 20 steps each (2^20 > 500000). Exec-uniform: no divergence;
    // loads broadcast from the same cacheline across all lanes.
    int s0 = 0, s1 = 0;
    const int g1 = g + 1;
    #pragma unroll
    for (int step = 1 << 19; step > 0; step >>= 1) {
        const int c0 = s0 + step;
        const int c1 = s1 + step;
        if (c0 <= n_nodes && batch[c0 - 1] < g)  s0 = c0;
        if (c1 <= n_nodes && batch[c1 - 1] < g1) s1 = c1;
    }
    const int seg_start = s0;
    const int seg_end   = s1;
    const int seg_len   = seg_end - seg_start;

    // Wave's contiguous quarter of the segment.
    const int q   = (seg_len + 3) >> 2;
    const int ws_ = seg_start + wv * q;
    const int we_ = min(ws_ + q, seg_end);

    const vfloat4* __restrict__ frow = reinterpret_cast<const vfloat4*>(features);
    const vfloat4* __restrict__ W4   = reinterpret_cast<const vfloat4*>(W_att);

    // Lane's W fragment: channels {4*(sub+16j) .. +3}, j=0..3.
    const vfloat4 w0 = W4[sub];
    const vfloat4 w1 = W4[sub + 16];
    const vfloat4 w2 = W4[sub + 32];
    const vfloat4 w3 = W4[sub + 48];
    const float bias = b_att[0];

    vfloat4 acc0 = 0.f, acc1 = 0.f, acc2 = 0.f, acc3 = 0.f;

    int n = ws_;
    // 3-stage pipeline buffers (stage = 4 rows; this wave's lane reads 4x16B).
    vfloat4 a0, a1, a2, a3;   // rows n .. n+3
    vfloat4 b0, b1, b2, b3;   // rows n+4 .. n+7

    if (n + 4 <= we_) {
        const size_t rb = (size_t)(n + grp) * kVecPerRow + sub;
        a0 = __builtin_nontemporal_load(&frow[rb]);
        a1 = __builtin_nontemporal_load(&frow[rb + 16]);
        a2 = __builtin_nontemporal_load(&frow[rb + 32]);
        a3 = __builtin_nontemporal_load(&frow[rb + 48]);
    }
    if (n + 8 <= we_) {
        const size_t rb = (size_t)(n + 4 + grp) * kVecPerRow + sub;
        b0 = __builtin_nontemporal_load(&frow[rb]);
        b1 = __builtin_nontemporal_load(&frow[rb + 16]);
        b2 = __builtin_nontemporal_load(&frow[rb + 32]);
        b3 = __builtin_nontemporal_load(&frow[rb + 48]);
    }

    #define HGP_COMPUTE(r0, r1, r2, r3)                                        \
        do {                                                                   \
            float p = dot4(r0, w0) + dot4(r1, w1) + dot4(r2, w2) + dot4(r3, w3); \
            p += __shfl_xor(p, 8, 64);                                         \
            p += __shfl_xor(p, 4, 64);                                         \
            p += __shfl_xor(p, 2, 64);                                         \
            p += __shfl_xor(p, 1, 64);                                         \
            const float gate = sigmoidf(p + bias);                             \
            acc0 += r0 * gate; acc1 += r1 * gate;                              \
            acc2 += r2 * gate; acc3 += r3 * gate;                              \
        } while (0)

    for (; n + 12 <= we_; n += 4) {
        // Issue stage-3 loads (rows n+8..n+11) before consuming stage-1.
        const size_t rb = (size_t)(n + 8 + grp) * kVecPerRow + sub;
        vfloat4 c0 = __builtin_nontemporal_load(&frow[rb]);
        vfloat4 c1 = __builtin_nontemporal_load(&frow[rb + 16]);
        vfloat4 c2 = __builtin_nontemporal_load(&frow[rb + 32]);
        vfloat4 c3 = __builtin_nontemporal_load(&frow[rb + 48]);

        HGP_COMPUTE(a0, a1, a2, a3);

        a0 = b0; a1 = b1; a2 = b2; a3 = b3;
        b0 = c0; b1 = c1; b2 = c2; b3 = c3;
    }

    if (n + 4 <= we_) {  // drain stage 1
        HGP_COMPUTE(a0, a1, a2, a3);
        n += 4;
        a0 = b0; a1 = b1; a2 = b2; a3 = b3;
    }
    if (n + 4 <= we_) {  // drain stage 2
        HGP_COMPUTE(a0, a1, a2, a3);
        n += 4;
    }

    if (n < we_) {  // masked tail: 1..3 rows; out-of-range groups contribute 0
        const int  row = n + grp;
        const bool ok  = row < we_;
        const size_t rb = (size_t)(ok ? row : we_ - 1) * kVecPerRow + sub;
        vfloat4 t0 = __builtin_nontemporal_load(&frow[rb]);
        vfloat4 t1 = __builtin_nontemporal_load(&frow[rb + 16]);
        vfloat4 t2 = __builtin_nontemporal_load(&frow[rb + 32]);
        vfloat4 t3 = __builtin_nontemporal_load(&frow[rb + 48]);
        if (!ok) { t0 = 0.f; t1 = 0.f; t2 = 0.f; t3 = 0.f; }
        HGP_COMPUTE(t0, t1, t2, t3);
    }
    #undef HGP_COMPUTE

    // 16 partial channel-vectors (4 waves x 4 groups) -> LDS -> one store.
    __shared__ float lds[16][kChannels];  // 16 KB
    {
        const int slot = wv * 4 + grp;
        vfloat4* dst = reinterpret_cast<vfloat4*>(lds[slot]);
        dst[sub]      = acc0;
        dst[sub + 16] = acc1;
        dst[sub + 32] = acc2;
        dst[sub + 48] = acc3;
    }
    __syncthreads();

    const int t = threadIdx.x;  // 0..255 == channel
    float s = 0.f;
    #pragma unroll
    for (int k = 0; k < 16; ++k) s += lds[k][t];
    out[(size_t)g * kChannels + t] = s;
}

extern "C" void kernel_launch(void* const* d_in, const int* in_sizes, int n_in,
                              void* d_out, int out_size, void* d_ws, size_t ws_size,
                              hipStream_t stream) {
    const float* features = (const float*)d_in[0];
    const int*   batch    = (const int*)d_in[1];
    const float* W_att    = (const float*)d_in[2];
    const float* b_att    = (const float*)d_in[3];
    float*       out      = (float*)d_out;
    (void)d_ws; (void)ws_size;  // unused — the 2 GB poison fill happens anyway (R6)

    const int n_nodes    = in_sizes[1];          // one batch entry per node
    const int num_graphs = out_size / kChannels; // 2048

    hgp_seg_kernel<<<num_graphs, 256, 0, stream>>>(features, batch, W_att, b_att,
                                                   out, n_nodes);
}